// Round 1
// baseline (922.259 us; speedup 1.0000x reference)
//
#include <hip/hip_runtime.h>

#define NN 100000
#define NE 3200000
#define NF 512
#define ND 64
#define NC 10
#define NB 391            // ceil(NN/256)

// workspace layout (4-byte elements)
#define OFF_H      0          // NN*ND  h = x @ (W1*M1); rank[] aliases first NE
#define OFF_RANK   0          //        (consumed by fill before gemm1 writes h)
#define OFF_DIS    6400000    // NN     deg^-1/2
#define OFF_W1     6500000    // NF*ND  Weff1
#define OFF_W2     6532768    // ND*NC  Weff2
#define OFF_CNT    6533408    // NN     int in-degree histogram
#define OFF_RP     6633408    // NN+1   int CSR rowptr
#define OFF_BSUM   6733409    // 512    int block sums for scan
#define OFF_EDGE   6733922    // NE int2 {src, bits(w)}  (8B-aligned: even)
// total = 13,133,922 * 4B = 52.5 MB

// cnt=0, masked weights
__global__ __launch_bounds__(256) void prep_kernel(
    const float* __restrict__ W1, const float* __restrict__ M1,
    const float* __restrict__ W2, const float* __restrict__ M2,
    float* __restrict__ ws) {
  const int i = blockIdx.x * 256 + threadIdx.x;   // grid = NB
  if (i < NN) ((int*)ws)[OFF_CNT + i] = 0;
  if (i < NF * ND) ws[OFF_W1 + i] = W1[i] * M1[i];
  if (i < ND * NC) ws[OFF_W2 + i] = W2[i] * M2[i];
}

// the ONLY atomic pass: histogram + record each edge's intra-bucket rank
__global__ __launch_bounds__(256) void hist_kernel(
    const int* __restrict__ dst, int* __restrict__ cnt,
    int* __restrict__ rank) {
  const int e = blockIdx.x * 256 + threadIdx.x;   // grid covers exactly NE
  rank[e] = atomicAdd(&cnt[dst[e]], 1);
}

// per-block sums of cnt -> bsum
__global__ __launch_bounds__(256) void scan_partial(
    const int* __restrict__ cnt, int* __restrict__ bsum) {
  __shared__ int s[256];
  const int i = blockIdx.x * 256 + threadIdx.x;
  int v = (i < NN) ? cnt[i] : 0;
  s[threadIdx.x] = v; __syncthreads();
  for (int off = 128; off > 0; off >>= 1) {
    if (threadIdx.x < off) s[threadIdx.x] += s[threadIdx.x + off];
    __syncthreads();
  }
  if (threadIdx.x == 0) bsum[blockIdx.x] = s[0];
}

// exclusive scan of the NB block sums (single block)
__global__ __launch_bounds__(512) void scan_bsum(int* __restrict__ bsum) {
  __shared__ int s[512];
  const int t = threadIdx.x;
  const int v = (t < NB) ? bsum[t] : 0;
  s[t] = v; __syncthreads();
  for (int off = 1; off < 512; off <<= 1) {
    const int a = (t >= off) ? s[t - off] : 0;
    __syncthreads();
    s[t] += a;
    __syncthreads();
  }
  if (t < NB) bsum[t] = s[t] - v;   // exclusive
}

// per-block exclusive scan + offset -> rowptr
__global__ __launch_bounds__(256) void scan_final(
    const int* __restrict__ cnt, const int* __restrict__ bsum,
    int* __restrict__ rowptr) {
  __shared__ int s[256];
  const int i = blockIdx.x * 256 + threadIdx.x;
  const int v = (i < NN) ? cnt[i] : 0;
  s[threadIdx.x] = v; __syncthreads();
  for (int off = 1; off < 256; off <<= 1) {
    const int a = (threadIdx.x >= off) ? s[threadIdx.x - off] : 0;
    __syncthreads();
    s[threadIdx.x] += a;
    __syncthreads();
  }
  if (i < NN) {
    const int excl = s[threadIdx.x] - v + bsum[blockIdx.x];
    rowptr[i] = excl;
    if (i == NN - 1) rowptr[NN] = excl + v;   // == NE
  }
}

// atomic-free counting-sort fill: edge[rowptr[dst]+rank] = {src, w}
__global__ __launch_bounds__(256) void fill_kernel(
    const int* __restrict__ src, const int* __restrict__ dst,
    const float* __restrict__ ew, const int* __restrict__ rank,
    const int* __restrict__ rowptr, int2* __restrict__ edge) {
  const int e = blockIdx.x * 256 + threadIdx.x;   // grid covers exactly NE
  const int pos = rowptr[dst[e]] + rank[e];
  edge[pos] = make_int2(src[e], __float_as_int(ew[e]));
}

// deg[n] = 1 + row-sum of w; dis = rsqrt(deg). Thread per node.
__global__ __launch_bounds__(256) void degdis_kernel(
    const int* __restrict__ rowptr, const int2* __restrict__ edge,
    float* __restrict__ dis) {
  const int n = blockIdx.x * 256 + threadIdx.x;
  if (n >= NN) return;
  const int beg = rowptr[n], end = rowptr[n + 1];
  float s = 1.0f;                         // self-loop weight
  for (int e = beg; e < end; ++e) s += __int_as_float(edge[e].y);
  dis[n] = rsqrtf(s);
}

// h[n][d] = sum_k x[n][k] * Weff1[k][d].
// 8 nodes per wave; x rows are wave-uniform -> scalar (SGPR) loads, no LDS.
// The x operand feeds all 64 d-lanes, so it belongs in SGPRs:
// v_fmac_f32 acc, s_x, v_w (one SGPR src per VALU op is legal).
// w columns stay per-lane in VGPRs (L2-resident; 8 nodes/wave halves w L2
// traffic vs 4 nodes/wave).
__global__ __launch_bounds__(256) void gemm1_kernel(
    const float* __restrict__ x, const float* __restrict__ w,
    float* __restrict__ h) {
  const int lane = threadIdx.x & 63;
  const int wid = __builtin_amdgcn_readfirstlane(threadIdx.x >> 6);  // force wave-uniform
  const size_t row0 = ((size_t)blockIdx.x * 4 + (size_t)wid) * 8;    // 32 nodes/block
  const float* __restrict__ xr = x + row0 * NF;
  float acc[8];
#pragma unroll
  for (int n = 0; n < 8; ++n) acc[n] = 0.0f;
#pragma unroll 2
  for (int k = 0; k < NF; k += 8) {
    float wv[8];
#pragma unroll
    for (int kk = 0; kk < 8; ++kk) wv[kk] = w[(k + kk) * ND + lane];  // coalesced 256B/wave
#pragma unroll
    for (int n = 0; n < 8; ++n) {
      const float* __restrict__ xp = xr + n * NF + k;  // uniform addr -> s_load_dwordx8
      float a = acc[n];
      a = fmaf(xp[0], wv[0], a); a = fmaf(xp[1], wv[1], a);
      a = fmaf(xp[2], wv[2], a); a = fmaf(xp[3], wv[3], a);
      a = fmaf(xp[4], wv[4], a); a = fmaf(xp[5], wv[5], a);
      a = fmaf(xp[6], wv[6], a); a = fmaf(xp[7], wv[7], a);
      acc[n] = a;
    }
  }
  float* __restrict__ hp = h + row0 * ND + lane;
#pragma unroll
  for (int n = 0; n < 8; ++n) hp[n * ND] = acc[n];   // coalesced 256B/row
}

// One wave per dst node.  Row result = dis[n] * Σ_e (w·dis[src])·h[src][lane],
// then fused self-loop, bias, ReLU and 64x10 classifier.
__global__ __launch_bounds__(256) void gather_kernel(
    const int* __restrict__ rowptr, const int2* __restrict__ edge,
    const float* __restrict__ h, const float* __restrict__ dis,
    const float* __restrict__ b1, const float* __restrict__ w2,
    const float* __restrict__ b2, float* __restrict__ out) {
  const int lane = threadIdx.x & 63;
  const int n = (blockIdx.x * 256 + threadIdx.x) >> 6;
  if (n >= NN) return;
  const int beg = rowptr[n];
  const int end = rowptr[n + 1];
  float s0 = 0.0f, s1 = 0.0f, s2 = 0.0f, s3 = 0.0f;
  for (int base = beg; base < end; base += 64) {
    int c = 0; float p = 0.0f;
    const int e = base + lane;
    if (e < end) {                      // coalesced 8B/lane batch load
      const int2 ed = edge[e];
      c = ed.x;
      p = __int_as_float(ed.y) * dis[c];   // w * dis[src]  (L2-resident gather)
    }
    const int m = min(64, end - base);
    int j = 0;
    for (; j + 4 <= m; j += 4) {        // 4 independent gather chains
      const int   c0 = __shfl(c, j, 64),     c1 = __shfl(c, j + 1, 64);
      const int   c2 = __shfl(c, j + 2, 64), c3 = __shfl(c, j + 3, 64);
      const float p0 = __shfl(p, j, 64),     p1 = __shfl(p, j + 1, 64);
      const float p2 = __shfl(p, j + 2, 64), p3 = __shfl(p, j + 3, 64);
      const float h0 = h[(size_t)c0 * ND + lane];
      const float h1 = h[(size_t)c1 * ND + lane];
      const float h2 = h[(size_t)c2 * ND + lane];
      const float h3 = h[(size_t)c3 * ND + lane];
      s0 = fmaf(h0, p0, s0); s1 = fmaf(h1, p1, s1);
      s2 = fmaf(h2, p2, s2); s3 = fmaf(h3, p3, s3);
    }
    for (; j < m; ++j) {
      const int cc = __shfl(c, j, 64);
      const float pp = __shfl(p, j, 64);
      s0 = fmaf(h[(size_t)cc * ND + lane], pp, s0);
    }
  }
  const float dn = dis[n];
  const float hn = h[(size_t)n * ND + lane];
  float vv = fmaf(((s0 + s1) + (s2 + s3)) + hn * dn, dn, b1[lane]);
  vv = fmaxf(vv, 0.0f);
  float res = 0.0f;
#pragma unroll
  for (int cix = 0; cix < NC; ++cix) {
    float q = vv * w2[lane * NC + cix];
#pragma unroll
    for (int off = 32; off > 0; off >>= 1) q += __shfl_xor(q, off, 64);
    if (lane == cix) res = q + b2[cix];
  }
  if (lane < NC) out[n * NC + lane] = res;
}

extern "C" void kernel_launch(void* const* d_in, const int* in_sizes, int n_in,
                              void* d_out, int out_size, void* d_ws, size_t ws_size,
                              hipStream_t stream) {
  const float* x  = (const float*)d_in[0];
  const int*   ei = (const int*)d_in[1];   // (2, NE) row-major int32
  const float* ew = (const float*)d_in[2];
  const float* W1 = (const float*)d_in[3];
  const float* M1 = (const float*)d_in[4];
  const float* b1 = (const float*)d_in[5];
  const float* W2 = (const float*)d_in[6];
  const float* M2 = (const float*)d_in[7];
  const float* b2 = (const float*)d_in[8];
  float* out = (float*)d_out;
  float* ws  = (float*)d_ws;
  int*   wsi = (int*)d_ws;
  const int* src = ei;
  const int* dst = ei + NE;
  int2* edge = (int2*)(wsi + OFF_EDGE);

  prep_kernel<<<NB, 256, 0, stream>>>(W1, M1, W2, M2, ws);
  hist_kernel<<<NE / 256, 256, 0, stream>>>(dst, wsi + OFF_CNT, wsi + OFF_RANK);
  scan_partial<<<NB, 256, 0, stream>>>(wsi + OFF_CNT, wsi + OFF_BSUM);
  scan_bsum<<<1, 512, 0, stream>>>(wsi + OFF_BSUM);
  scan_final<<<NB, 256, 0, stream>>>(wsi + OFF_CNT, wsi + OFF_BSUM, wsi + OFF_RP);
  fill_kernel<<<NE / 256, 256, 0, stream>>>(src, dst, ew, wsi + OFF_RANK,
                                            wsi + OFF_RP, edge);
  degdis_kernel<<<NB, 256, 0, stream>>>(wsi + OFF_RP, edge, ws + OFF_DIS);
  gemm1_kernel<<<NN / 32, 256, 0, stream>>>(x, ws + OFF_W1, ws + OFF_H);
  gather_kernel<<<NN / 4, 256, 0, stream>>>(wsi + OFF_RP, edge, ws + OFF_H,
                                            ws + OFF_DIS, b1, ws + OFF_W2, b2, out);
}

// Round 2
// 736.673 us; speedup vs baseline: 1.2519x; 1.2519x over previous
//
#include <hip/hip_runtime.h>

#define NN 100000
#define NE 3200000
#define NF 512
#define ND 64
#define NC 10
#define NB 391            // ceil(NN/256)

// workspace layout (4-byte elements)
#define OFF_H      0          // NN*ND  h = x @ (W1*M1); rank[] aliases first NE
#define OFF_RANK   0          //        (consumed by fill before gemm1 writes h)
#define OFF_DIS    6400000    // NN     deg^-1/2
#define OFF_W1     6500000    // NF*ND floats = 128KB: B-fragment array (bf16 hi/lo)
#define OFF_W2     6532768    // ND*NC  Weff2
#define OFF_CNT    6533408    // NN     int in-degree histogram
#define OFF_RP     6633408    // NN+1   int CSR rowptr
#define OFF_BSUM   6733409    // 512    int block sums for scan
#define OFF_EDGE   6733922    // NE int2 {src, bits(w)}  (8B-aligned: even)
// total = 13,133,922 * 4B = 52.5 MB

typedef __attribute__((ext_vector_type(8))) short v8s;   // 8 bf16 = 4 VGPRs
typedef __attribute__((ext_vector_type(4))) float v4f;

// round-to-nearest-even fp32 -> bf16 (upper 16 bits)
__device__ __forceinline__ unsigned short bf16_rne(float f) {
  unsigned int u = __float_as_uint(f);
  return (unsigned short)((u + 0x7fffu + ((u >> 16) & 1u)) >> 16);
}

// cnt=0, masked classifier weights, and W1eff pre-split into bf16 hi/lo
// MFMA B-fragments.  Fragment layout (MUST match gemm1_kernel):
//   k-step s = k>>5, lane-group g = (k>>3)&3, elem e = k&7, tile t = d>>4,
//   lane = (g<<4)|(d&15).  Byte offset ((s*4+t)*64+lane)*32 + e*2 (hi), +16 (lo).
// A and B use the SAME k->(g,e) mapping, so the MFMA result is invariant to
// the hardware's internal k-order (any consistent k-permutation cancels).
__global__ __launch_bounds__(256) void prep_kernel(
    const float* __restrict__ W1, const float* __restrict__ M1,
    const float* __restrict__ W2, const float* __restrict__ M2,
    float* __restrict__ ws) {
  const int i = blockIdx.x * 256 + threadIdx.x;   // grid = NB
  if (i < NN) ((int*)ws)[OFF_CNT + i] = 0;
  if (i < NF * ND) {
    const float v = W1[i] * M1[i];
    const int k = i >> 6, d = i & 63;             // i = k*ND + d
    const int s = k >> 5, g = (k >> 3) & 3, e = k & 7;
    const int t = d >> 4;
    const int lane = (g << 4) | (d & 15);
    unsigned short* bp = (unsigned short*)(ws + OFF_W1);
    const int base = ((s * 4 + t) * 64 + lane) * 16 + e;
    const unsigned short hb = bf16_rne(v);
    bp[base] = hb;
    bp[base + 8] = bf16_rne(v - __uint_as_float((unsigned int)hb << 16));
  }
  if (i < ND * NC) ws[OFF_W2 + i] = W2[i] * M2[i];
}

// the ONLY atomic pass: histogram + record each edge's intra-bucket rank
__global__ __launch_bounds__(256) void hist_kernel(
    const int* __restrict__ dst, int* __restrict__ cnt,
    int* __restrict__ rank) {
  const int e = blockIdx.x * 256 + threadIdx.x;   // grid covers exactly NE
  rank[e] = atomicAdd(&cnt[dst[e]], 1);
}

// per-block sums of cnt -> bsum
__global__ __launch_bounds__(256) void scan_partial(
    const int* __restrict__ cnt, int* __restrict__ bsum) {
  __shared__ int s[256];
  const int i = blockIdx.x * 256 + threadIdx.x;
  int v = (i < NN) ? cnt[i] : 0;
  s[threadIdx.x] = v; __syncthreads();
  for (int off = 128; off > 0; off >>= 1) {
    if (threadIdx.x < off) s[threadIdx.x] += s[threadIdx.x + off];
    __syncthreads();
  }
  if (threadIdx.x == 0) bsum[blockIdx.x] = s[0];
}

// exclusive scan of the NB block sums (single block)
__global__ __launch_bounds__(512) void scan_bsum(int* __restrict__ bsum) {
  __shared__ int s[512];
  const int t = threadIdx.x;
  const int v = (t < NB) ? bsum[t] : 0;
  s[t] = v; __syncthreads();
  for (int off = 1; off < 512; off <<= 1) {
    const int a = (t >= off) ? s[t - off] : 0;
    __syncthreads();
    s[t] += a;
    __syncthreads();
  }
  if (t < NB) bsum[t] = s[t] - v;   // exclusive
}

// per-block exclusive scan + offset -> rowptr
__global__ __launch_bounds__(256) void scan_final(
    const int* __restrict__ cnt, const int* __restrict__ bsum,
    int* __restrict__ rowptr) {
  __shared__ int s[256];
  const int i = blockIdx.x * 256 + threadIdx.x;
  const int v = (i < NN) ? cnt[i] : 0;
  s[threadIdx.x] = v; __syncthreads();
  for (int off = 1; off < 256; off <<= 1) {
    const int a = (threadIdx.x >= off) ? s[threadIdx.x - off] : 0;
    __syncthreads();
    s[threadIdx.x] += a;
    __syncthreads();
  }
  if (i < NN) {
    const int excl = s[threadIdx.x] - v + bsum[blockIdx.x];
    rowptr[i] = excl;
    if (i == NN - 1) rowptr[NN] = excl + v;   // == NE
  }
}

// atomic-free counting-sort fill: edge[rowptr[dst]+rank] = {src, w}
__global__ __launch_bounds__(256) void fill_kernel(
    const int* __restrict__ src, const int* __restrict__ dst,
    const float* __restrict__ ew, const int* __restrict__ rank,
    const int* __restrict__ rowptr, int2* __restrict__ edge) {
  const int e = blockIdx.x * 256 + threadIdx.x;   // grid covers exactly NE
  const int pos = rowptr[dst[e]] + rank[e];
  edge[pos] = make_int2(src[e], __float_as_int(ew[e]));
}

// deg[n] = 1 + row-sum of w; dis = rsqrt(deg). Thread per node.
__global__ __launch_bounds__(256) void degdis_kernel(
    const int* __restrict__ rowptr, const int2* __restrict__ edge,
    float* __restrict__ dis) {
  const int n = blockIdx.x * 256 + threadIdx.x;
  if (n >= NN) return;
  const int beg = rowptr[n], end = rowptr[n + 1];
  float s = 1.0f;                         // self-loop weight
  for (int e = beg; e < end; ++e) s += __int_as_float(edge[e].y);
  dis[n] = rsqrtf(s);
}

// h = x @ Weff1 via bf16-split MFMA: x=xh+xl, w=wh+wl (RNE splits),
// acc += xh*wh + xh*wl + xl*wh in fp32 (xl*wl ~2^-18 rel, dropped).
// Wave = 32 nodes x 64 dims: 2 M-frags x 4 N-tiles of 16x16, K-loop 16x32.
// A frags load straight from global (each x element read exactly once,
// 128B-contiguous per row segment); B frags are the prep-arranged array
// (L2-resident, 2 coalesced dwordx4 per tile per step).
// C layout (m89-verified): col = lane&15, row = (lane>>4)*4 + reg.
__global__ __launch_bounds__(256) void gemm1_kernel(
    const float* __restrict__ x, const float* __restrict__ bfrag_f,
    float* __restrict__ h) {
  const int lane = threadIdx.x & 63;
  const int wid  = threadIdx.x >> 6;
  const size_t row0 = ((size_t)blockIdx.x * 4 + wid) * 32;
  if (row0 >= NN) return;
  const int lr = lane & 15;               // A row / B col / C col within tile
  const int lg = lane >> 4;               // k-group
  const float* x0 = x + (row0 + lr) * NF + lg * 8;
  const v8s* bfr = (const v8s*)bfrag_f + (size_t)lane * 2;  // 32B per lane
  v4f acc[2][4];
#pragma unroll
  for (int i = 0; i < 2; ++i)
#pragma unroll
    for (int t = 0; t < 4; ++t) acc[i][t] = (v4f){0.f, 0.f, 0.f, 0.f};

  for (int s = 0; s < 16; ++s) {          // k0 = s*32
    v8s ah[2], al[2];
#pragma unroll
    for (int i = 0; i < 2; ++i) {
      const float* xp = x0 + (size_t)i * (16 * NF) + s * 32;
      const float4 p0 = *(const float4*)xp;
      const float4 p1 = *(const float4*)(xp + 4);
      const float vv[8] = {p0.x, p0.y, p0.z, p0.w, p1.x, p1.y, p1.z, p1.w};
#pragma unroll
      for (int e = 0; e < 8; ++e) {
        const unsigned short hb = bf16_rne(vv[e]);
        ah[i][e] = (short)hb;
        al[i][e] = (short)bf16_rne(vv[e] - __uint_as_float((unsigned int)hb << 16));
      }
    }
#pragma unroll
    for (int t = 0; t < 4; ++t) {
      const v8s bh = bfr[(size_t)(s * 4 + t) * 128];      // hi frag
      const v8s bl = bfr[(size_t)(s * 4 + t) * 128 + 1];  // lo frag
#pragma unroll
      for (int i = 0; i < 2; ++i) {
        acc[i][t] = __builtin_amdgcn_mfma_f32_16x16x32_bf16(ah[i], bh, acc[i][t], 0, 0, 0);
        acc[i][t] = __builtin_amdgcn_mfma_f32_16x16x32_bf16(ah[i], bl, acc[i][t], 0, 0, 0);
        acc[i][t] = __builtin_amdgcn_mfma_f32_16x16x32_bf16(al[i], bh, acc[i][t], 0, 0, 0);
      }
    }
  }
  // C[row=(lane>>4)*4+r][col=lane&15] per 16x16 tile (m89-verified layout)
#pragma unroll
  for (int i = 0; i < 2; ++i)
#pragma unroll
    for (int t = 0; t < 4; ++t)
#pragma unroll
      for (int r = 0; r < 4; ++r)
        h[(row0 + i * 16 + lg * 4 + r) * ND + t * 16 + lr] = acc[i][t][r];
}

// One wave per dst node.  Row result = dis[n] * Σ_e (w·dis[src])·h[src][lane],
// then fused self-loop, bias, ReLU and 64x10 classifier.
__global__ __launch_bounds__(256) void gather_kernel(
    const int* __restrict__ rowptr, const int2* __restrict__ edge,
    const float* __restrict__ h, const float* __restrict__ dis,
    const float* __restrict__ b1, const float* __restrict__ w2,
    const float* __restrict__ b2, float* __restrict__ out) {
  const int lane = threadIdx.x & 63;
  const int n = (blockIdx.x * 256 + threadIdx.x) >> 6;
  if (n >= NN) return;
  const int beg = rowptr[n];
  const int end = rowptr[n + 1];
  float s0 = 0.0f, s1 = 0.0f, s2 = 0.0f, s3 = 0.0f;
  for (int base = beg; base < end; base += 64) {
    int c = 0; float p = 0.0f;
    const int e = base + lane;
    if (e < end) {                      // coalesced 8B/lane batch load
      const int2 ed = edge[e];
      c = ed.x;
      p = __int_as_float(ed.y) * dis[c];   // w * dis[src]  (L2-resident gather)
    }
    const int m = min(64, end - base);
    int j = 0;
    for (; j + 4 <= m; j += 4) {        // 4 independent gather chains
      const int   c0 = __shfl(c, j, 64),     c1 = __shfl(c, j + 1, 64);
      const int   c2 = __shfl(c, j + 2, 64), c3 = __shfl(c, j + 3, 64);
      const float p0 = __shfl(p, j, 64),     p1 = __shfl(p, j + 1, 64);
      const float p2 = __shfl(p, j + 2, 64), p3 = __shfl(p, j + 3, 64);
      const float h0 = h[(size_t)c0 * ND + lane];
      const float h1 = h[(size_t)c1 * ND + lane];
      const float h2 = h[(size_t)c2 * ND + lane];
      const float h3 = h[(size_t)c3 * ND + lane];
      s0 = fmaf(h0, p0, s0); s1 = fmaf(h1, p1, s1);
      s2 = fmaf(h2, p2, s2); s3 = fmaf(h3, p3, s3);
    }
    for (; j < m; ++j) {
      const int cc = __shfl(c, j, 64);
      const float pp = __shfl(p, j, 64);
      s0 = fmaf(h[(size_t)cc * ND + lane], pp, s0);
    }
  }
  const float dn = dis[n];
  const float hn = h[(size_t)n * ND + lane];
  float vv = fmaf(((s0 + s1) + (s2 + s3)) + hn * dn, dn, b1[lane]);
  vv = fmaxf(vv, 0.0f);
  float res = 0.0f;
#pragma unroll
  for (int cix = 0; cix < NC; ++cix) {
    float q = vv * w2[lane * NC + cix];
#pragma unroll
    for (int off = 32; off > 0; off >>= 1) q += __shfl_xor(q, off, 64);
    if (lane == cix) res = q + b2[cix];
  }
  if (lane < NC) out[n * NC + lane] = res;
}

extern "C" void kernel_launch(void* const* d_in, const int* in_sizes, int n_in,
                              void* d_out, int out_size, void* d_ws, size_t ws_size,
                              hipStream_t stream) {
  const float* x  = (const float*)d_in[0];
  const int*   ei = (const int*)d_in[1];   // (2, NE) row-major int32
  const float* ew = (const float*)d_in[2];
  const float* W1 = (const float*)d_in[3];
  const float* M1 = (const float*)d_in[4];
  const float* b1 = (const float*)d_in[5];
  const float* W2 = (const float*)d_in[6];
  const float* M2 = (const float*)d_in[7];
  const float* b2 = (const float*)d_in[8];
  float* out = (float*)d_out;
  float* ws  = (float*)d_ws;
  int*   wsi = (int*)d_ws;
  const int* src = ei;
  const int* dst = ei + NE;
  int2* edge = (int2*)(wsi + OFF_EDGE);

  prep_kernel<<<NB, 256, 0, stream>>>(W1, M1, W2, M2, ws);
  hist_kernel<<<NE / 256, 256, 0, stream>>>(dst, wsi + OFF_CNT, wsi + OFF_RANK);
  scan_partial<<<NB, 256, 0, stream>>>(wsi + OFF_CNT, wsi + OFF_BSUM);
  scan_bsum<<<1, 512, 0, stream>>>(wsi + OFF_BSUM);
  scan_final<<<NB, 256, 0, stream>>>(wsi + OFF_CNT, wsi + OFF_BSUM, wsi + OFF_RP);
  fill_kernel<<<NE / 256, 256, 0, stream>>>(src, dst, ew, wsi + OFF_RANK,
                                            wsi + OFF_RP, edge);
  degdis_kernel<<<NB, 256, 0, stream>>>(wsi + OFF_RP, edge, ws + OFF_DIS);
  gemm1_kernel<<<(NN + 127) / 128, 256, 0, stream>>>(x, ws + OFF_W1, ws + OFF_H);
  gather_kernel<<<NN / 4, 256, 0, stream>>>(wsi + OFF_RP, edge, ws + OFF_H,
                                            ws + OFF_DIS, b1, ws + OFF_W2, b2, out);
}